// Round 1
// baseline (686.148 us; speedup 1.0000x reference)
//
#include <hip/hip_runtime.h>
#include <hip/hip_bf16.h>

// ===================== preprocessing: degree / CSR build =====================

__global__ void k_count_deg(const int* __restrict__ dst, int* __restrict__ deg, int E) {
    int e = blockIdx.x * blockDim.x + threadIdx.x;
    if (e < E) atomicAdd(&deg[dst[e]], 1);
}

__global__ void k_dinv(const int* __restrict__ deg, float* __restrict__ dinv, int N) {
    int i = blockIdx.x * blockDim.x + threadIdx.x;
    if (i < N) dinv[i] = rsqrtf((float)deg[i] + 1.0f);
}

// per-chunk sums (chunk = 1024 elements)
__global__ void k_chunk_sums(const int* __restrict__ deg, int* __restrict__ partial, int N) {
    __shared__ int wsum[16];
    int t = threadIdx.x;
    int i = blockIdx.x * 1024 + t;
    int v = (i < N) ? deg[i] : 0;
    for (int off = 32; off > 0; off >>= 1) v += __shfl_down(v, off, 64);
    if ((t & 63) == 0) wsum[t >> 6] = v;
    __syncthreads();
    if (t == 0) {
        int s = 0;
        #pragma unroll
        for (int k = 0; k < 16; ++k) s += wsum[k];
        partial[blockIdx.x] = s;
    }
}

__global__ void k_scan_partials(int* partial, int NB) {
    if (threadIdx.x == 0 && blockIdx.x == 0) {
        int run = 0;
        for (int b = 0; b < NB; ++b) { int t = partial[b]; partial[b] = run; run += t; }
    }
}

__global__ void k_chunk_scan(const int* __restrict__ deg, const int* __restrict__ partial,
                             int* __restrict__ row_start, int N) {
    __shared__ int s[1024];
    int t = threadIdx.x;
    int i = blockIdx.x * 1024 + t;
    int v = (i < N) ? deg[i] : 0;
    s[t] = v;
    __syncthreads();
    for (int off = 1; off < 1024; off <<= 1) {
        int x = (t >= off) ? s[t - off] : 0;
        __syncthreads();
        s[t] += x;
        __syncthreads();
    }
    // inclusive -> exclusive; also writes row_start[N] = E (deg reads 0 past N)
    if (i <= N) row_start[i] = partial[blockIdx.x] + s[t] - v;
}

__global__ void k_scatter(const int* __restrict__ src, const int* __restrict__ dst,
                          const int* __restrict__ row_start, int* __restrict__ fill,
                          int* __restrict__ col, int E) {
    int e = blockIdx.x * blockDim.x + threadIdx.x;
    if (e < E) {
        int d = dst[e];
        int r = atomicAdd(&fill[d], 1);
        col[row_start[d] + r] = src[e];
    }
}

// ===================== fp32 tiled GEMM: C[N x BN] = A[N x 128] @ W[128 x BN] =====================
// block = (16,16); tile = 128 rows x BN cols; micro-tile 8 x TN per thread; K = 128 in chunks of 16.

template<int BN, int TN>
__global__ void k_gemm(const float* __restrict__ A, const float* __restrict__ W,
                       float* __restrict__ C, int N) {
    __shared__ float As[16][129];   // [k][row], +1 pad
    __shared__ float Bs[16][BN];    // [k][col]
    const int tx = threadIdx.x, ty = threadIdx.y;
    const int tid = ty * 16 + tx;
    const int row0 = blockIdx.x * 128;

    float acc[8][TN];
    #pragma unroll
    for (int i = 0; i < 8; ++i)
        #pragma unroll
        for (int j = 0; j < TN; ++j) acc[i][j] = 0.f;

    for (int k0 = 0; k0 < 128; k0 += 16) {
        // stage A tile: 128 rows x 16 cols = 512 float4; 2 per thread
        #pragma unroll
        for (int r = 0; r < 2; ++r) {
            int f4 = tid + r * 256;
            int arow = f4 >> 2;
            int ac4 = f4 & 3;
            float4 v = make_float4(0.f, 0.f, 0.f, 0.f);
            int grow = row0 + arow;
            if (grow < N) v = *(const float4*)&A[(size_t)grow * 128 + k0 + ac4 * 4];
            As[ac4 * 4 + 0][arow] = v.x;
            As[ac4 * 4 + 1][arow] = v.y;
            As[ac4 * 4 + 2][arow] = v.z;
            As[ac4 * 4 + 3][arow] = v.w;
        }
        // stage B tile: 16 x BN floats = BN*4 float4s
        #pragma unroll
        for (int r = 0; r < BN / 64; ++r) {
            int f4 = tid + r * 256;
            int brow = f4 / (BN / 4);
            int bc4 = f4 % (BN / 4);
            float4 v = *(const float4*)&W[(size_t)(k0 + brow) * BN + bc4 * 4];
            *(float4*)&Bs[brow][bc4 * 4] = v;
        }
        __syncthreads();
        #pragma unroll
        for (int kk = 0; kk < 16; ++kk) {
            float a[8], bb[TN];
            #pragma unroll
            for (int i = 0; i < 8; ++i) a[i] = As[kk][ty * 8 + i];
            #pragma unroll
            for (int j = 0; j < TN; ++j) bb[j] = Bs[kk][tx * TN + j];
            #pragma unroll
            for (int i = 0; i < 8; ++i)
                #pragma unroll
                for (int j = 0; j < TN; ++j) acc[i][j] += a[i] * bb[j];
        }
        __syncthreads();
    }
    // store (vectorized, TN is 4 or 8)
    #pragma unroll
    for (int i = 0; i < 8; ++i) {
        int grow = row0 + ty * 8 + i;
        if (grow < N) {
            #pragma unroll
            for (int j = 0; j < TN; j += 4) {
                float4 v = make_float4(acc[i][j], acc[i][j + 1], acc[i][j + 2], acc[i][j + 3]);
                *(float4*)&C[(size_t)grow * BN + tx * TN + j] = v;
            }
        }
    }
}

// ===================== aggregation: out = relu(dinv_i * sum(dinv_s * t_s) + dinv_i^2 * t_i + b) ==========
// one 64-lane wave per node; D = 128 (float2/lane) or 64 (float/lane)

template<int D>
__global__ void k_agg(const float* __restrict__ t, float* __restrict__ outp,
                      const int* __restrict__ row_start, const int* __restrict__ col,
                      const float* __restrict__ dinv, const float* __restrict__ bias,
                      int N) {
    int gid = blockIdx.x * blockDim.x + threadIdx.x;
    int node = gid >> 6;
    int lane = gid & 63;
    if (node >= N) return;
    int p = row_start[node];
    int end = row_start[node + 1];
    if (D == 128) {
        const float2* tp = (const float2*)t;
        float2 a0 = make_float2(0.f, 0.f), a1 = make_float2(0.f, 0.f);
        for (; p + 1 < end; p += 2) {
            int s0 = col[p], s1 = col[p + 1];
            float w0 = dinv[s0], w1 = dinv[s1];
            float2 v0 = tp[s0 * 64 + lane];
            float2 v1 = tp[s1 * 64 + lane];
            a0.x += w0 * v0.x; a0.y += w0 * v0.y;
            a1.x += w1 * v1.x; a1.y += w1 * v1.y;
        }
        if (p < end) {
            int s0 = col[p];
            float w0 = dinv[s0];
            float2 v0 = tp[s0 * 64 + lane];
            a0.x += w0 * v0.x; a0.y += w0 * v0.y;
        }
        float di = dinv[node];
        float2 sv = tp[node * 64 + lane];
        float2 bv = ((const float2*)bias)[lane];
        float rx = di * (a0.x + a1.x) + di * di * sv.x + bv.x;
        float ry = di * (a0.y + a1.y) + di * di * sv.y + bv.y;
        float2 r;
        r.x = fmaxf(rx, 0.f);
        r.y = fmaxf(ry, 0.f);
        ((float2*)outp)[node * 64 + lane] = r;
    } else {
        float a0 = 0.f, a1 = 0.f;
        for (; p + 1 < end; p += 2) {
            int s0 = col[p], s1 = col[p + 1];
            a0 += dinv[s0] * t[s0 * 64 + lane];
            a1 += dinv[s1] * t[s1 * 64 + lane];
        }
        if (p < end) {
            int s0 = col[p];
            a0 += dinv[s0] * t[s0 * 64 + lane];
        }
        float di = dinv[node];
        float r = di * (a0 + a1) + di * di * t[node * 64 + lane] + bias[lane];
        outp[node * 64 + lane] = fmaxf(r, 0.f);
    }
}

// ===================== final: out[i] = h3[i,:] . Wf + bf =====================

__global__ void k_final(const float* __restrict__ h, const float* __restrict__ Wf,
                        const float* __restrict__ bf, float* __restrict__ out, int N) {
    int gid = blockIdx.x * blockDim.x + threadIdx.x;
    int node = gid >> 6;
    int lane = gid & 63;
    if (node >= N) return;
    float v = h[node * 64 + lane] * Wf[lane];
    for (int off = 32; off > 0; off >>= 1) v += __shfl_down(v, off, 64);
    if (lane == 0) out[node] = v + bf[0];
}

// ===================== launch =====================

extern "C" void kernel_launch(void* const* d_in, const int* in_sizes, int n_in,
                              void* d_out, int out_size, void* d_ws, size_t ws_size,
                              hipStream_t stream) {
    const float* x  = (const float*)d_in[0];
    const int*   src = (const int*)d_in[1];
    const int*   dst = (const int*)d_in[2];
    const float* W1 = (const float*)d_in[3];
    const float* b1 = (const float*)d_in[4];
    const float* W2 = (const float*)d_in[5];
    const float* b2 = (const float*)d_in[6];
    const float* W3 = (const float*)d_in[7];
    const float* b3 = (const float*)d_in[8];
    const float* Wf = (const float*)d_in[9];
    const float* bf = (const float*)d_in[10];
    float* out = (float*)d_out;

    const int N = 50000;
    const int E = 800000;

    char* ws = (char*)d_ws;
    size_t off = 0;
    auto alloc = [&](size_t bytes) -> void* {
        void* p = (void*)(ws + off);
        off += (bytes + 511) & ~((size_t)511);
        return p;
    };
    int*   deg       = (int*)alloc((size_t)N * 4);
    float* dinv      = (float*)alloc((size_t)N * 4);
    int*   row_start = (int*)alloc((size_t)(N + 1) * 4);
    int*   fill      = (int*)alloc((size_t)N * 4);
    int*   partial   = (int*)alloc(64 * 4);
    int*   col       = (int*)alloc((size_t)E * 4);
    float* bufA      = (float*)alloc((size_t)N * 128 * 4);
    float* bufB      = (float*)alloc((size_t)N * 128 * 4);

    hipMemsetAsync(deg, 0, (size_t)N * 4, stream);
    hipMemsetAsync(fill, 0, (size_t)N * 4, stream);

    k_count_deg<<<(E + 255) / 256, 256, 0, stream>>>(dst, deg, E);
    k_dinv<<<(N + 255) / 256, 256, 0, stream>>>(deg, dinv, N);
    int NB = (N + 1023) / 1024;
    k_chunk_sums<<<NB, 1024, 0, stream>>>(deg, partial, N);
    k_scan_partials<<<1, 64, 0, stream>>>(partial, NB);
    k_chunk_scan<<<NB, 1024, 0, stream>>>(deg, partial, row_start, N);
    k_scatter<<<(E + 255) / 256, 256, 0, stream>>>(src, dst, row_start, fill, col, E);

    dim3 tb(16, 16);
    int gemmGrid = (N + 127) / 128;
    int aggGrid = (N * 64 + 255) / 256;

    // layer 1: t = x @ W1 ; h = relu(agg(t) + b1)
    k_gemm<128, 8><<<gemmGrid, tb, 0, stream>>>(x, W1, bufA, N);
    k_agg<128><<<aggGrid, 256, 0, stream>>>(bufA, bufB, row_start, col, dinv, b1, N);
    // layer 2
    k_gemm<128, 8><<<gemmGrid, tb, 0, stream>>>(bufB, W2, bufA, N);
    k_agg<128><<<aggGrid, 256, 0, stream>>>(bufA, bufB, row_start, col, dinv, b2, N);
    // layer 3 (transform to 64 dims first, then aggregate 64 dims — same math, half the gather)
    k_gemm<64, 4><<<gemmGrid, tb, 0, stream>>>(bufB, W3, bufA, N);
    k_agg<64><<<aggGrid, 256, 0, stream>>>(bufA, bufB, row_start, col, dinv, b3, N);
    // final linear
    k_final<<<aggGrid, 256, 0, stream>>>(bufB, Wf, bf, out, N);
}

// Round 2
// 503.388 us; speedup vs baseline: 1.3631x; 1.3631x over previous
//
#include <hip/hip_runtime.h>
#include <hip/hip_bf16.h>

// ===================== preprocessing: degree / CSR build =====================

__global__ __launch_bounds__(256) void k_count_deg(const int* __restrict__ dst, int* __restrict__ deg, int E) {
    int e = blockIdx.x * blockDim.x + threadIdx.x;
    if (e < E) atomicAdd(&deg[dst[e]], 1);
}

__global__ __launch_bounds__(256) void k_dinv(const int* __restrict__ deg, float* __restrict__ dinv, int N) {
    int i = blockIdx.x * blockDim.x + threadIdx.x;
    if (i < N) dinv[i] = rsqrtf((float)deg[i] + 1.0f);
}

// per-chunk sums (chunk = 1024 elements)
__global__ __launch_bounds__(1024) void k_chunk_sums(const int* __restrict__ deg, int* __restrict__ partial, int N) {
    __shared__ int wsum[16];
    int t = threadIdx.x;
    int i = blockIdx.x * 1024 + t;
    int v = (i < N) ? deg[i] : 0;
    for (int off = 32; off > 0; off >>= 1) v += __shfl_down(v, off, 64);
    if ((t & 63) == 0) wsum[t >> 6] = v;
    __syncthreads();
    if (t == 0) {
        int s = 0;
        #pragma unroll
        for (int k = 0; k < 16; ++k) s += wsum[k];
        partial[blockIdx.x] = s;
    }
}

__global__ void k_scan_partials(int* partial, int NB) {
    if (threadIdx.x == 0 && blockIdx.x == 0) {
        int run = 0;
        for (int b = 0; b < NB; ++b) { int t = partial[b]; partial[b] = run; run += t; }
    }
}

__global__ __launch_bounds__(1024) void k_chunk_scan(const int* __restrict__ deg, const int* __restrict__ partial,
                             int* __restrict__ row_start, int N) {
    __shared__ int s[1024];
    int t = threadIdx.x;
    int i = blockIdx.x * 1024 + t;
    int v = (i < N) ? deg[i] : 0;
    s[t] = v;
    __syncthreads();
    for (int off = 1; off < 1024; off <<= 1) {
        int x = (t >= off) ? s[t - off] : 0;
        __syncthreads();
        s[t] += x;
        __syncthreads();
    }
    // inclusive -> exclusive; also writes row_start[N] = E (deg reads 0 past N)
    if (i <= N) row_start[i] = partial[blockIdx.x] + s[t] - v;
}

__global__ __launch_bounds__(256) void k_scatter(const int* __restrict__ src, const int* __restrict__ dst,
                          const int* __restrict__ row_start, int* __restrict__ fill,
                          int* __restrict__ col, int E) {
    int e = blockIdx.x * blockDim.x + threadIdx.x;
    if (e < E) {
        int d = dst[e];
        int r = atomicAdd(&fill[d], 1);
        col[row_start[d] + r] = src[e];
    }
}

// ===================== fp32 tiled GEMM: C[N x BN] = A[N x 128] @ W[128 x BN] =====================
// block = (16,16); tile = 128 rows x BN cols; micro-tile 8 x TN per thread; K = 128 in chunks of 16.
// __launch_bounds__(256): without it hipcc assumes 1024-thread blocks, caps VGPRs at 64,
// and SPILLS the 8x8 accumulator (R1: 313 MB scratch writes, 150 us/dispatch).

template<int BN, int TN>
__global__ __launch_bounds__(256) void k_gemm(const float* __restrict__ A, const float* __restrict__ W,
                       float* __restrict__ C, int N) {
    __shared__ float As[16][129];   // [k][row], +1 pad
    __shared__ float Bs[16][BN];    // [k][col]
    const int tx = threadIdx.x, ty = threadIdx.y;
    const int tid = ty * 16 + tx;
    const int row0 = blockIdx.x * 128;

    float acc[8][TN];
    #pragma unroll
    for (int i = 0; i < 8; ++i)
        #pragma unroll
        for (int j = 0; j < TN; ++j) acc[i][j] = 0.f;

    for (int k0 = 0; k0 < 128; k0 += 16) {
        // stage A tile: 128 rows x 16 cols = 512 float4; 2 per thread
        #pragma unroll
        for (int r = 0; r < 2; ++r) {
            int f4 = tid + r * 256;
            int arow = f4 >> 2;
            int ac4 = f4 & 3;
            float4 v = make_float4(0.f, 0.f, 0.f, 0.f);
            int grow = row0 + arow;
            if (grow < N) v = *(const float4*)&A[(size_t)grow * 128 + k0 + ac4 * 4];
            As[ac4 * 4 + 0][arow] = v.x;
            As[ac4 * 4 + 1][arow] = v.y;
            As[ac4 * 4 + 2][arow] = v.z;
            As[ac4 * 4 + 3][arow] = v.w;
        }
        // stage B tile: 16 x BN floats = BN*4 float4s
        #pragma unroll
        for (int r = 0; r < BN / 64; ++r) {
            int f4 = tid + r * 256;
            int brow = f4 / (BN / 4);
            int bc4 = f4 % (BN / 4);
            float4 v = *(const float4*)&W[(size_t)(k0 + brow) * BN + bc4 * 4];
            *(float4*)&Bs[brow][bc4 * 4] = v;
        }
        __syncthreads();
        #pragma unroll
        for (int kk = 0; kk < 16; ++kk) {
            float a[8], bb[TN];
            #pragma unroll
            for (int i = 0; i < 8; ++i) a[i] = As[kk][ty * 8 + i];
            #pragma unroll
            for (int j = 0; j < TN; ++j) bb[j] = Bs[kk][tx * TN + j];
            #pragma unroll
            for (int i = 0; i < 8; ++i)
                #pragma unroll
                for (int j = 0; j < TN; ++j) acc[i][j] += a[i] * bb[j];
        }
        __syncthreads();
    }
    // store (vectorized, TN is 4 or 8)
    #pragma unroll
    for (int i = 0; i < 8; ++i) {
        int grow = row0 + ty * 8 + i;
        if (grow < N) {
            #pragma unroll
            for (int j = 0; j < TN; j += 4) {
                float4 v = make_float4(acc[i][j], acc[i][j + 1], acc[i][j + 2], acc[i][j + 3]);
                *(float4*)&C[(size_t)grow * BN + tx * TN + j] = v;
            }
        }
    }
}

// ===================== aggregation: out = relu(dinv_i * sum(dinv_s * t_s) + dinv_i^2 * t_i + b) ==========
// one 64-lane wave per node; D=128 (float2/lane)

__global__ __launch_bounds__(256) void k_agg128(const float* __restrict__ t, float* __restrict__ outp,
                      const int* __restrict__ row_start, const int* __restrict__ col,
                      const float* __restrict__ dinv, const float* __restrict__ bias,
                      int N) {
    int gid = blockIdx.x * blockDim.x + threadIdx.x;
    int node = gid >> 6;
    int lane = gid & 63;
    if (node >= N) return;
    int p = row_start[node];
    int end = row_start[node + 1];
    const float2* tp = (const float2*)t;
    float2 a0 = make_float2(0.f, 0.f), a1 = make_float2(0.f, 0.f);
    for (; p + 1 < end; p += 2) {
        int s0 = col[p], s1 = col[p + 1];
        float w0 = dinv[s0], w1 = dinv[s1];
        float2 v0 = tp[s0 * 64 + lane];
        float2 v1 = tp[s1 * 64 + lane];
        a0.x += w0 * v0.x; a0.y += w0 * v0.y;
        a1.x += w1 * v1.x; a1.y += w1 * v1.y;
    }
    if (p < end) {
        int s0 = col[p];
        float w0 = dinv[s0];
        float2 v0 = tp[s0 * 64 + lane];
        a0.x += w0 * v0.x; a0.y += w0 * v0.y;
    }
    float di = dinv[node];
    float2 sv = tp[node * 64 + lane];
    float2 bv = ((const float2*)bias)[lane];
    float rx = di * (a0.x + a1.x) + di * di * sv.x + bv.x;
    float ry = di * (a0.y + a1.y) + di * di * sv.y + bv.y;
    float2 r;
    r.x = fmaxf(rx, 0.f);
    r.y = fmaxf(ry, 0.f);
    ((float2*)outp)[node * 64 + lane] = r;
}

// layer-3 aggregation (D=64) fused with final linear: out[i] = relu(agg_i) . Wf + bf
__global__ __launch_bounds__(256) void k_agg64_final(const float* __restrict__ t, float* __restrict__ outp,
                      const int* __restrict__ row_start, const int* __restrict__ col,
                      const float* __restrict__ dinv, const float* __restrict__ bias,
                      const float* __restrict__ Wf, const float* __restrict__ bf,
                      int N) {
    int gid = blockIdx.x * blockDim.x + threadIdx.x;
    int node = gid >> 6;
    int lane = gid & 63;
    if (node >= N) return;
    int p = row_start[node];
    int end = row_start[node + 1];
    float a0 = 0.f, a1 = 0.f;
    for (; p + 1 < end; p += 2) {
        int s0 = col[p], s1 = col[p + 1];
        a0 += dinv[s0] * t[s0 * 64 + lane];
        a1 += dinv[s1] * t[s1 * 64 + lane];
    }
    if (p < end) {
        int s0 = col[p];
        a0 += dinv[s0] * t[s0 * 64 + lane];
    }
    float di = dinv[node];
    float r = di * (a0 + a1) + di * di * t[node * 64 + lane] + bias[lane];
    r = fmaxf(r, 0.f);
    // fused final dot product: out[node] = sum_lane(r * Wf[lane]) + bf
    float v = r * Wf[lane];
    for (int off = 32; off > 0; off >>= 1) v += __shfl_down(v, off, 64);
    if (lane == 0) outp[node] = v + bf[0];
}

// ===================== launch =====================

extern "C" void kernel_launch(void* const* d_in, const int* in_sizes, int n_in,
                              void* d_out, int out_size, void* d_ws, size_t ws_size,
                              hipStream_t stream) {
    const float* x  = (const float*)d_in[0];
    const int*   src = (const int*)d_in[1];
    const int*   dst = (const int*)d_in[2];
    const float* W1 = (const float*)d_in[3];
    const float* b1 = (const float*)d_in[4];
    const float* W2 = (const float*)d_in[5];
    const float* b2 = (const float*)d_in[6];
    const float* W3 = (const float*)d_in[7];
    const float* b3 = (const float*)d_in[8];
    const float* Wf = (const float*)d_in[9];
    const float* bf = (const float*)d_in[10];
    float* out = (float*)d_out;

    const int N = 50000;
    const int E = 800000;

    char* ws = (char*)d_ws;
    size_t off = 0;
    auto alloc = [&](size_t bytes) -> void* {
        void* p = (void*)(ws + off);
        off += (bytes + 511) & ~((size_t)511);
        return p;
    };
    int*   deg       = (int*)alloc((size_t)N * 4);
    float* dinv      = (float*)alloc((size_t)N * 4);
    int*   row_start = (int*)alloc((size_t)(N + 1) * 4);
    int*   fill      = (int*)alloc((size_t)N * 4);
    int*   partial   = (int*)alloc(64 * 4);
    int*   col       = (int*)alloc((size_t)E * 4);
    float* bufA      = (float*)alloc((size_t)N * 128 * 4);
    float* bufB      = (float*)alloc((size_t)N * 128 * 4);

    hipMemsetAsync(deg, 0, (size_t)N * 4, stream);
    hipMemsetAsync(fill, 0, (size_t)N * 4, stream);

    k_count_deg<<<(E + 255) / 256, 256, 0, stream>>>(dst, deg, E);
    k_dinv<<<(N + 255) / 256, 256, 0, stream>>>(deg, dinv, N);
    int NB = (N + 1023) / 1024;
    k_chunk_sums<<<NB, 1024, 0, stream>>>(deg, partial, N);
    k_scan_partials<<<1, 64, 0, stream>>>(partial, NB);
    k_chunk_scan<<<NB, 1024, 0, stream>>>(deg, partial, row_start, N);
    k_scatter<<<(E + 255) / 256, 256, 0, stream>>>(src, dst, row_start, fill, col, E);

    dim3 tb(16, 16);
    int gemmGrid = (N + 127) / 128;
    int aggGrid = (N * 64 + 255) / 256;

    // layer 1: t = x @ W1 ; h = relu(agg(t) + b1)
    k_gemm<128, 8><<<gemmGrid, tb, 0, stream>>>(x, W1, bufA, N);
    k_agg128<<<aggGrid, 256, 0, stream>>>(bufA, bufB, row_start, col, dinv, b1, N);
    // layer 2
    k_gemm<128, 8><<<gemmGrid, tb, 0, stream>>>(bufB, W2, bufA, N);
    k_agg128<<<aggGrid, 256, 0, stream>>>(bufA, bufB, row_start, col, dinv, b2, N);
    // layer 3 (transform to 64 dims first, then aggregate + fused final linear)
    k_gemm<64, 4><<<gemmGrid, tb, 0, stream>>>(bufB, W3, bufA, N);
    k_agg64_final<<<aggGrid, 256, 0, stream>>>(bufA, out, row_start, col, dinv, b3, Wf, bf, N);
}

// Round 3
// 484.397 us; speedup vs baseline: 1.4165x; 1.0392x over previous
//
#include <hip/hip_runtime.h>
#include <hip/hip_bf16.h>

// ===================== preprocessing: degree / CSR build =====================

__global__ __launch_bounds__(256) void k_count_deg(const int* __restrict__ dst, int* __restrict__ deg, int E) {
    int e = blockIdx.x * blockDim.x + threadIdx.x;
    if (e < E) atomicAdd(&deg[dst[e]], 1);
}

__global__ __launch_bounds__(256) void k_dinv(const int* __restrict__ deg, float* __restrict__ dinv, int N) {
    int i = blockIdx.x * blockDim.x + threadIdx.x;
    if (i < N) dinv[i] = rsqrtf((float)deg[i] + 1.0f);
}

__global__ __launch_bounds__(1024) void k_chunk_sums(const int* __restrict__ deg, int* __restrict__ partial, int N) {
    __shared__ int wsum[16];
    int t = threadIdx.x;
    int i = blockIdx.x * 1024 + t;
    int v = (i < N) ? deg[i] : 0;
    for (int off = 32; off > 0; off >>= 1) v += __shfl_down(v, off, 64);
    if ((t & 63) == 0) wsum[t >> 6] = v;
    __syncthreads();
    if (t == 0) {
        int s = 0;
        #pragma unroll
        for (int k = 0; k < 16; ++k) s += wsum[k];
        partial[blockIdx.x] = s;
    }
}

__global__ void k_scan_partials(int* partial, int NB) {
    if (threadIdx.x == 0 && blockIdx.x == 0) {
        int run = 0;
        for (int b = 0; b < NB; ++b) { int t = partial[b]; partial[b] = run; run += t; }
    }
}

__global__ __launch_bounds__(1024) void k_chunk_scan(const int* __restrict__ deg, const int* __restrict__ partial,
                             int* __restrict__ row_start, int N) {
    __shared__ int s[1024];
    int t = threadIdx.x;
    int i = blockIdx.x * 1024 + t;
    int v = (i < N) ? deg[i] : 0;
    s[t] = v;
    __syncthreads();
    for (int off = 1; off < 1024; off <<= 1) {
        int x = (t >= off) ? s[t - off] : 0;
        __syncthreads();
        s[t] += x;
        __syncthreads();
    }
    if (i <= N) row_start[i] = partial[blockIdx.x] + s[t] - v;
}

// scatter src index AND per-edge weight dinv[src] (dinv[dst] factor is hoisted in agg)
__global__ __launch_bounds__(256) void k_scatter(const int* __restrict__ src, const int* __restrict__ dst,
                          const int* __restrict__ row_start, int* __restrict__ fill,
                          const float* __restrict__ dinv,
                          int* __restrict__ col, float* __restrict__ val, int E) {
    int e = blockIdx.x * blockDim.x + threadIdx.x;
    if (e < E) {
        int d = dst[e];
        int s = src[e];
        int r = atomicAdd(&fill[d], 1);
        int slot = row_start[d] + r;
        col[slot] = s;
        val[slot] = dinv[s];
    }
}

// ===================== fp32 tiled GEMM: C[N x BN] = A[N x 128] @ W[128 x BN] =====================
// BM=128, BK=32, software-pipelined: prefetch next K-chunk into regs while computing current.
// __launch_bounds__(256,3): cap VGPR ~170 so 3 blocks/CU co-reside (R1 lesson: no bound => spills).

template<int BN, int TN>
__global__ __launch_bounds__(256, 3) void k_gemm(const float* __restrict__ A, const float* __restrict__ W,
                       float* __restrict__ C, int N) {
    __shared__ float As[32][129];   // [k][row], +1 pad
    __shared__ float Bs[32][BN];    // [k][col]
    const int tx = threadIdx.x, ty = threadIdx.y;
    const int tid = ty * 16 + tx;
    const int row0 = blockIdx.x * 128;
    constexpr int NB4 = BN / 4;            // float4 per B row
    constexpr int BREG = (32 * BN / 4) / 256; // B float4s per thread (4 or 2)

    float4 aReg[4], bReg[BREG];

    auto loadA = [&](int k0) {
        #pragma unroll
        for (int r = 0; r < 4; ++r) {
            int f4 = tid + r * 256;
            int ar = f4 >> 3, c4 = f4 & 7;
            int grow = row0 + ar;
            aReg[r] = (grow < N) ? *(const float4*)&A[(size_t)grow * 128 + k0 + c4 * 4]
                                 : make_float4(0.f, 0.f, 0.f, 0.f);
        }
    };
    auto loadB = [&](int k0) {
        #pragma unroll
        for (int r = 0; r < BREG; ++r) {
            int f4 = tid + r * 256;
            int br = f4 / NB4, c4 = f4 % NB4;
            bReg[r] = *(const float4*)&W[(size_t)(k0 + br) * BN + c4 * 4];
        }
    };
    auto stage = [&]() {
        #pragma unroll
        for (int r = 0; r < 4; ++r) {
            int f4 = tid + r * 256;
            int ar = f4 >> 3, c4 = f4 & 7;
            As[c4 * 4 + 0][ar] = aReg[r].x;
            As[c4 * 4 + 1][ar] = aReg[r].y;
            As[c4 * 4 + 2][ar] = aReg[r].z;
            As[c4 * 4 + 3][ar] = aReg[r].w;
        }
        #pragma unroll
        for (int r = 0; r < BREG; ++r) {
            int f4 = tid + r * 256;
            int br = f4 / NB4, c4 = f4 % NB4;
            *(float4*)&Bs[br][c4 * 4] = bReg[r];
        }
    };

    float acc[8][TN];
    #pragma unroll
    for (int i = 0; i < 8; ++i)
        #pragma unroll
        for (int j = 0; j < TN; ++j) acc[i][j] = 0.f;

    loadA(0); loadB(0);
    for (int c = 0; c < 4; ++c) {
        stage();
        __syncthreads();
        if (c < 3) { loadA((c + 1) * 32); loadB((c + 1) * 32); }
        #pragma unroll
        for (int kk = 0; kk < 32; ++kk) {
            float a[8], bb[TN];
            #pragma unroll
            for (int i = 0; i < 8; ++i) a[i] = As[kk][ty * 8 + i];
            #pragma unroll
            for (int j = 0; j < TN; ++j) bb[j] = Bs[kk][tx * TN + j];
            #pragma unroll
            for (int i = 0; i < 8; ++i)
                #pragma unroll
                for (int j = 0; j < TN; ++j) acc[i][j] += a[i] * bb[j];
        }
        __syncthreads();
    }

    #pragma unroll
    for (int i = 0; i < 8; ++i) {
        int grow = row0 + ty * 8 + i;
        if (grow < N) {
            #pragma unroll
            for (int j = 0; j < TN; j += 4) {
                float4 v = make_float4(acc[i][j], acc[i][j + 1], acc[i][j + 2], acc[i][j + 3]);
                *(float4*)&C[(size_t)grow * BN + tx * TN + j] = v;
            }
        }
    }
}

// ===================== aggregation =====================
// One wave per node. Edge indices + weights for up to 64 edges loaded in ONE coalesced
// load, broadcast via __shfl (no per-edge index/weight memory ops). 8 gathers in flight.

__global__ __launch_bounds__(256) void k_agg128(const float* __restrict__ t, float* __restrict__ outp,
                      const int* __restrict__ row_start, const int* __restrict__ col,
                      const float* __restrict__ val,
                      const float* __restrict__ dinv, const float* __restrict__ bias,
                      int N) {
    int gid = blockIdx.x * blockDim.x + threadIdx.x;
    int node = gid >> 6;
    int lane = gid & 63;
    if (node >= N) return;
    int p = row_start[node];
    int end = row_start[node + 1];
    const float2* tp = (const float2*)t;
    float2 acc[4];
    #pragma unroll
    for (int j = 0; j < 4; ++j) acc[j] = make_float2(0.f, 0.f);

    while (p < end) {
        int idx = p + lane;
        int myc = (idx < end) ? col[idx] : 0;
        float myw = (idx < end) ? val[idx] : 0.f;
        int cnt = min(end - p, 64);
        int e = 0;
        for (; e + 8 <= cnt; e += 8) {
            int s[8]; float w[8];
            #pragma unroll
            for (int j = 0; j < 8; ++j) { s[j] = __shfl(myc, e + j); w[j] = __shfl(myw, e + j); }
            float2 v[8];
            #pragma unroll
            for (int j = 0; j < 8; ++j) v[j] = tp[s[j] * 64 + lane];
            #pragma unroll
            for (int j = 0; j < 8; ++j) {
                acc[j & 3].x += w[j] * v[j].x;
                acc[j & 3].y += w[j] * v[j].y;
            }
        }
        for (; e + 4 <= cnt; e += 4) {
            int s[4]; float w[4];
            #pragma unroll
            for (int j = 0; j < 4; ++j) { s[j] = __shfl(myc, e + j); w[j] = __shfl(myw, e + j); }
            float2 v[4];
            #pragma unroll
            for (int j = 0; j < 4; ++j) v[j] = tp[s[j] * 64 + lane];
            #pragma unroll
            for (int j = 0; j < 4; ++j) {
                acc[j].x += w[j] * v[j].x;
                acc[j].y += w[j] * v[j].y;
            }
        }
        for (; e < cnt; ++e) {
            int s0 = __shfl(myc, e); float w0 = __shfl(myw, e);
            float2 v0 = tp[s0 * 64 + lane];
            acc[0].x += w0 * v0.x;
            acc[0].y += w0 * v0.y;
        }
        p += 64;
    }
    float di = dinv[node];
    float2 sv = tp[node * 64 + lane];
    float2 bv = ((const float2*)bias)[lane];
    float sx = acc[0].x + acc[1].x + acc[2].x + acc[3].x;
    float sy = acc[0].y + acc[1].y + acc[2].y + acc[3].y;
    float2 r;
    r.x = fmaxf(di * sx + di * di * sv.x + bv.x, 0.f);
    r.y = fmaxf(di * sy + di * di * sv.y + bv.y, 0.f);
    ((float2*)outp)[node * 64 + lane] = r;
}

// layer-3 aggregation (D=64) fused with final linear: out[i] = relu(agg_i + b) . Wf + bf
__global__ __launch_bounds__(256) void k_agg64_final(const float* __restrict__ t, float* __restrict__ outp,
                      const int* __restrict__ row_start, const int* __restrict__ col,
                      const float* __restrict__ val,
                      const float* __restrict__ dinv, const float* __restrict__ bias,
                      const float* __restrict__ Wf, const float* __restrict__ bf,
                      int N) {
    int gid = blockIdx.x * blockDim.x + threadIdx.x;
    int node = gid >> 6;
    int lane = gid & 63;
    if (node >= N) return;
    int p = row_start[node];
    int end = row_start[node + 1];
    float acc[4] = {0.f, 0.f, 0.f, 0.f};

    while (p < end) {
        int idx = p + lane;
        int myc = (idx < end) ? col[idx] : 0;
        float myw = (idx < end) ? val[idx] : 0.f;
        int cnt = min(end - p, 64);
        int e = 0;
        for (; e + 8 <= cnt; e += 8) {
            int s[8]; float w[8];
            #pragma unroll
            for (int j = 0; j < 8; ++j) { s[j] = __shfl(myc, e + j); w[j] = __shfl(myw, e + j); }
            float v[8];
            #pragma unroll
            for (int j = 0; j < 8; ++j) v[j] = t[s[j] * 64 + lane];
            #pragma unroll
            for (int j = 0; j < 8; ++j) acc[j & 3] += w[j] * v[j];
        }
        for (; e + 4 <= cnt; e += 4) {
            int s[4]; float w[4];
            #pragma unroll
            for (int j = 0; j < 4; ++j) { s[j] = __shfl(myc, e + j); w[j] = __shfl(myw, e + j); }
            float v[4];
            #pragma unroll
            for (int j = 0; j < 4; ++j) v[j] = t[s[j] * 64 + lane];
            #pragma unroll
            for (int j = 0; j < 4; ++j) acc[j] += w[j] * v[j];
        }
        for (; e < cnt; ++e) {
            int s0 = __shfl(myc, e); float w0 = __shfl(myw, e);
            acc[0] += w0 * t[s0 * 64 + lane];
        }
        p += 64;
    }
    float di = dinv[node];
    float r = di * (acc[0] + acc[1] + acc[2] + acc[3]) + di * di * t[node * 64 + lane] + bias[lane];
    r = fmaxf(r, 0.f);
    float v = r * Wf[lane];
    for (int off = 32; off > 0; off >>= 1) v += __shfl_down(v, off, 64);
    if (lane == 0) outp[node] = v + bf[0];
}

// ===================== launch =====================

extern "C" void kernel_launch(void* const* d_in, const int* in_sizes, int n_in,
                              void* d_out, int out_size, void* d_ws, size_t ws_size,
                              hipStream_t stream) {
    const float* x  = (const float*)d_in[0];
    const int*   src = (const int*)d_in[1];
    const int*   dst = (const int*)d_in[2];
    const float* W1 = (const float*)d_in[3];
    const float* b1 = (const float*)d_in[4];
    const float* W2 = (const float*)d_in[5];
    const float* b2 = (const float*)d_in[6];
    const float* W3 = (const float*)d_in[7];
    const float* b3 = (const float*)d_in[8];
    const float* Wf = (const float*)d_in[9];
    const float* bf = (const float*)d_in[10];
    float* out = (float*)d_out;

    const int N = 50000;
    const int E = 800000;

    char* ws = (char*)d_ws;
    size_t off = 0;
    auto alloc = [&](size_t bytes) -> void* {
        void* p = (void*)(ws + off);
        off += (bytes + 511) & ~((size_t)511);
        return p;
    };
    int*   deg       = (int*)alloc((size_t)N * 4);
    float* dinv      = (float*)alloc((size_t)N * 4);
    int*   row_start = (int*)alloc((size_t)(N + 1) * 4);
    int*   fill      = (int*)alloc((size_t)N * 4);
    int*   partial   = (int*)alloc(64 * 4);
    int*   col       = (int*)alloc((size_t)E * 4);
    float* val       = (float*)alloc((size_t)E * 4);
    float* bufA      = (float*)alloc((size_t)N * 128 * 4);
    float* bufB      = (float*)alloc((size_t)N * 128 * 4);

    hipMemsetAsync(deg, 0, (size_t)N * 4, stream);
    hipMemsetAsync(fill, 0, (size_t)N * 4, stream);

    k_count_deg<<<(E + 255) / 256, 256, 0, stream>>>(dst, deg, E);
    k_dinv<<<(N + 255) / 256, 256, 0, stream>>>(deg, dinv, N);
    int NB = (N + 1023) / 1024;
    k_chunk_sums<<<NB, 1024, 0, stream>>>(deg, partial, N);
    k_scan_partials<<<1, 64, 0, stream>>>(partial, NB);
    k_chunk_scan<<<NB, 1024, 0, stream>>>(deg, partial, row_start, N);
    k_scatter<<<(E + 255) / 256, 256, 0, stream>>>(src, dst, row_start, fill, dinv, col, val, E);

    dim3 tb(16, 16);
    int gemmGrid = (N + 127) / 128;
    int aggGrid = (N * 64 + 255) / 256;

    // layer 1: t = x @ W1 ; h = relu(agg(t) + b1)
    k_gemm<128, 8><<<gemmGrid, tb, 0, stream>>>(x, W1, bufA, N);
    k_agg128<<<aggGrid, 256, 0, stream>>>(bufA, bufB, row_start, col, val, dinv, b1, N);
    // layer 2
    k_gemm<128, 8><<<gemmGrid, tb, 0, stream>>>(bufB, W2, bufA, N);
    k_agg128<<<aggGrid, 256, 0, stream>>>(bufA, bufB, row_start, col, val, dinv, b2, N);
    // layer 3 (transform to 64 dims first, then aggregate + fused final linear)
    k_gemm<64, 4><<<gemmGrid, tb, 0, stream>>>(bufB, W3, bufA, N);
    k_agg64_final<<<aggGrid, 256, 0, stream>>>(bufA, out, row_start, col, val, dinv, b3, Wf, bf, N);
}

// Round 4
// 402.694 us; speedup vs baseline: 1.7039x; 1.2029x over previous
//
#include <hip/hip_runtime.h>
#include <hip/hip_bf16.h>

// ===================== preprocessing: degree / CSR build =====================

__global__ __launch_bounds__(256) void k_count_deg(const int* __restrict__ dst, int* __restrict__ deg, int E) {
    int e = blockIdx.x * blockDim.x + threadIdx.x;
    if (e < E) atomicAdd(&deg[dst[e]], 1);
}

__global__ __launch_bounds__(256) void k_dinv(const int* __restrict__ deg, float* __restrict__ dinv, int N) {
    int i = blockIdx.x * blockDim.x + threadIdx.x;
    if (i < N) dinv[i] = rsqrtf((float)deg[i] + 1.0f);
}

__global__ __launch_bounds__(1024) void k_chunk_sums(const int* __restrict__ deg, int* __restrict__ partial, int N) {
    __shared__ int wsum[16];
    int t = threadIdx.x;
    int i = blockIdx.x * 1024 + t;
    int v = (i < N) ? deg[i] : 0;
    for (int off = 32; off > 0; off >>= 1) v += __shfl_down(v, off, 64);
    if ((t & 63) == 0) wsum[t >> 6] = v;
    __syncthreads();
    if (t == 0) {
        int s = 0;
        #pragma unroll
        for (int k = 0; k < 16; ++k) s += wsum[k];
        partial[blockIdx.x] = s;
    }
}

__global__ void k_scan_partials(int* partial, int NB) {
    if (threadIdx.x == 0 && blockIdx.x == 0) {
        int run = 0;
        for (int b = 0; b < NB; ++b) { int t = partial[b]; partial[b] = run; run += t; }
    }
}

__global__ __launch_bounds__(1024) void k_chunk_scan(const int* __restrict__ deg, const int* __restrict__ partial,
                             int* __restrict__ row_start, int N) {
    __shared__ int s[1024];
    int t = threadIdx.x;
    int i = blockIdx.x * 1024 + t;
    int v = (i < N) ? deg[i] : 0;
    s[t] = v;
    __syncthreads();
    for (int off = 1; off < 1024; off <<= 1) {
        int x = (t >= off) ? s[t - off] : 0;
        __syncthreads();
        s[t] += x;
        __syncthreads();
    }
    if (i <= N) row_start[i] = partial[blockIdx.x] + s[t] - v;
}

// scatter src index AND per-edge weight dinv[src] (dinv[dst] factor is hoisted in agg)
__global__ __launch_bounds__(256) void k_scatter(const int* __restrict__ src, const int* __restrict__ dst,
                          const int* __restrict__ row_start, int* __restrict__ fill,
                          const float* __restrict__ dinv,
                          int* __restrict__ col, float* __restrict__ val, int E) {
    int e = blockIdx.x * blockDim.x + threadIdx.x;
    if (e < E) {
        int d = dst[e];
        int s = src[e];
        int r = atomicAdd(&fill[d], 1);
        int slot = row_start[d] + r;
        col[slot] = s;
        val[slot] = dinv[s];
    }
}

// ===================== fp32 tiled GEMM: C[N x BN] = A[N x 128] @ W[128 x BN] =====================
// BM=64 rows x BN cols per block; micro-tile 4 x TN per thread; BK=16.
// R3 lesson: register-prefetch double-buffer + 8x8 micro-tile => allocator spills
// (135 MB scratch writes). Fix: HALVE the accumulator (acc=32 regs, total ~80),
// (256,2) bound = 256-reg ceiling never hit; occupancy ~5-6 waves/SIMD hides staging.

template<int BN, int TN>
__global__ __launch_bounds__(256, 2) void k_gemm(const float* __restrict__ A, const float* __restrict__ W,
                       float* __restrict__ C, int N) {
    __shared__ float As[16][68];    // [k][row]; 68*4=272 B row stride: 16B-aligned, +pad
    __shared__ float Bs[16][BN];    // [k][col]; BN*4 row stride is 16B-aligned
    const int tx = threadIdx.x, ty = threadIdx.y;
    const int tid = ty * 16 + tx;
    const int row0 = blockIdx.x * 64;
    constexpr int NB4 = BN / 4;          // float4 per B row (32 or 16)
    constexpr int BPT = (16 * NB4) / 256; // B float4 per thread (2 or 1)

    float acc[4][TN];
    #pragma unroll
    for (int i = 0; i < 4; ++i)
        #pragma unroll
        for (int j = 0; j < TN; ++j) acc[i][j] = 0.f;

    for (int k0 = 0; k0 < 128; k0 += 16) {
        // stage A tile: 64 rows x 16 cols = 256 float4; 1 per thread
        {
            int arow = tid >> 2;         // 0..63
            int ac4 = tid & 3;           // 0..3
            int grow = row0 + arow;
            float4 v = make_float4(0.f, 0.f, 0.f, 0.f);
            if (grow < N) v = *(const float4*)&A[(size_t)grow * 128 + k0 + ac4 * 4];
            As[ac4 * 4 + 0][arow] = v.x;
            As[ac4 * 4 + 1][arow] = v.y;
            As[ac4 * 4 + 2][arow] = v.z;
            As[ac4 * 4 + 3][arow] = v.w;
        }
        // stage B tile: 16 x BN floats
        #pragma unroll
        for (int r = 0; r < BPT; ++r) {
            int f4 = tid + r * 256;
            int brow = f4 / NB4;
            int bc4 = f4 % NB4;
            float4 v = *(const float4*)&W[(size_t)(k0 + brow) * BN + bc4 * 4];
            *(float4*)&Bs[brow][bc4 * 4] = v;
        }
        __syncthreads();
        #pragma unroll
        for (int kk = 0; kk < 16; ++kk) {
            float4 av = *(const float4*)&As[kk][ty * 4];
            float a[4] = {av.x, av.y, av.z, av.w};
            float bb[TN];
            #pragma unroll
            for (int j = 0; j < TN; j += 4) {
                float4 bv = *(const float4*)&Bs[kk][tx * TN + j];
                bb[j] = bv.x; bb[j + 1] = bv.y; bb[j + 2] = bv.z; bb[j + 3] = bv.w;
            }
            #pragma unroll
            for (int i = 0; i < 4; ++i)
                #pragma unroll
                for (int j = 0; j < TN; ++j) acc[i][j] += a[i] * bb[j];
        }
        __syncthreads();
    }

    #pragma unroll
    for (int i = 0; i < 4; ++i) {
        int grow = row0 + ty * 4 + i;
        if (grow < N) {
            #pragma unroll
            for (int j = 0; j < TN; j += 4) {
                float4 v = make_float4(acc[i][j], acc[i][j + 1], acc[i][j + 2], acc[i][j + 3]);
                *(float4*)&C[(size_t)grow * BN + tx * TN + j] = v;
            }
        }
    }
}

// ===================== aggregation =====================
// One wave per node. Edge indices + weights for up to 64 edges loaded in ONE coalesced
// load, broadcast via __shfl (no per-edge index/weight memory ops). 8 gathers in flight.

__global__ __launch_bounds__(256) void k_agg128(const float* __restrict__ t, float* __restrict__ outp,
                      const int* __restrict__ row_start, const int* __restrict__ col,
                      const float* __restrict__ val,
                      const float* __restrict__ dinv, const float* __restrict__ bias,
                      int N) {
    int gid = blockIdx.x * blockDim.x + threadIdx.x;
    int node = gid >> 6;
    int lane = gid & 63;
    if (node >= N) return;
    int p = row_start[node];
    int end = row_start[node + 1];
    const float2* tp = (const float2*)t;
    float2 acc[4];
    #pragma unroll
    for (int j = 0; j < 4; ++j) acc[j] = make_float2(0.f, 0.f);

    while (p < end) {
        int idx = p + lane;
        int myc = (idx < end) ? col[idx] : 0;
        float myw = (idx < end) ? val[idx] : 0.f;
        int cnt = min(end - p, 64);
        int e = 0;
        for (; e + 8 <= cnt; e += 8) {
            int s[8]; float w[8];
            #pragma unroll
            for (int j = 0; j < 8; ++j) { s[j] = __shfl(myc, e + j); w[j] = __shfl(myw, e + j); }
            float2 v[8];
            #pragma unroll
            for (int j = 0; j < 8; ++j) v[j] = tp[s[j] * 64 + lane];
            #pragma unroll
            for (int j = 0; j < 8; ++j) {
                acc[j & 3].x += w[j] * v[j].x;
                acc[j & 3].y += w[j] * v[j].y;
            }
        }
        for (; e + 4 <= cnt; e += 4) {
            int s[4]; float w[4];
            #pragma unroll
            for (int j = 0; j < 4; ++j) { s[j] = __shfl(myc, e + j); w[j] = __shfl(myw, e + j); }
            float2 v[4];
            #pragma unroll
            for (int j = 0; j < 4; ++j) v[j] = tp[s[j] * 64 + lane];
            #pragma unroll
            for (int j = 0; j < 4; ++j) {
                acc[j].x += w[j] * v[j].x;
                acc[j].y += w[j] * v[j].y;
            }
        }
        for (; e < cnt; ++e) {
            int s0 = __shfl(myc, e); float w0 = __shfl(myw, e);
            float2 v0 = tp[s0 * 64 + lane];
            acc[0].x += w0 * v0.x;
            acc[0].y += w0 * v0.y;
        }
        p += 64;
    }
    float di = dinv[node];
    float2 sv = tp[node * 64 + lane];
    float2 bv = ((const float2*)bias)[lane];
    float sx = acc[0].x + acc[1].x + acc[2].x + acc[3].x;
    float sy = acc[0].y + acc[1].y + acc[2].y + acc[3].y;
    float2 r;
    r.x = fmaxf(di * sx + di * di * sv.x + bv.x, 0.f);
    r.y = fmaxf(di * sy + di * di * sv.y + bv.y, 0.f);
    ((float2*)outp)[node * 64 + lane] = r;
}

// layer-3 aggregation (D=64) fused with final linear: out[i] = relu(agg_i + b) . Wf + bf
__global__ __launch_bounds__(256) void k_agg64_final(const float* __restrict__ t, float* __restrict__ outp,
                      const int* __restrict__ row_start, const int* __restrict__ col,
                      const float* __restrict__ val,
                      const float* __restrict__ dinv, const float* __restrict__ bias,
                      const float* __restrict__ Wf, const float* __restrict__ bf,
                      int N) {
    int gid = blockIdx.x * blockDim.x + threadIdx.x;
    int node = gid >> 6;
    int lane = gid & 63;
    if (node >= N) return;
    int p = row_start[node];
    int end = row_start[node + 1];
    float acc[4] = {0.f, 0.f, 0.f, 0.f};

    while (p < end) {
        int idx = p + lane;
        int myc = (idx < end) ? col[idx] : 0;
        float myw = (idx < end) ? val[idx] : 0.f;
        int cnt = min(end - p, 64);
        int e = 0;
        for (; e + 8 <= cnt; e += 8) {
            int s[8]; float w[8];
            #pragma unroll
            for (int j = 0; j < 8; ++j) { s[j] = __shfl(myc, e + j); w[j] = __shfl(myw, e + j); }
            float v[8];
            #pragma unroll
            for (int j = 0; j < 8; ++j) v[j] = t[s[j] * 64 + lane];
            #pragma unroll
            for (int j = 0; j < 8; ++j) acc[j & 3] += w[j] * v[j];
        }
        for (; e + 4 <= cnt; e += 4) {
            int s[4]; float w[4];
            #pragma unroll
            for (int j = 0; j < 4; ++j) { s[j] = __shfl(myc, e + j); w[j] = __shfl(myw, e + j); }
            float v[4];
            #pragma unroll
            for (int j = 0; j < 4; ++j) v[j] = t[s[j] * 64 + lane];
            #pragma unroll
            for (int j = 0; j < 4; ++j) acc[j] += w[j] * v[j];
        }
        for (; e < cnt; ++e) {
            int s0 = __shfl(myc, e); float w0 = __shfl(myw, e);
            acc[0] += w0 * t[s0 * 64 + lane];
        }
        p += 64;
    }
    float di = dinv[node];
    float r = di * (acc[0] + acc[1] + acc[2] + acc[3]) + di * di * t[node * 64 + lane] + bias[lane];
    r = fmaxf(r, 0.f);
    float v = r * Wf[lane];
    for (int off = 32; off > 0; off >>= 1) v += __shfl_down(v, off, 64);
    if (lane == 0) outp[node] = v + bf[0];
}

// ===================== launch =====================

extern "C" void kernel_launch(void* const* d_in, const int* in_sizes, int n_in,
                              void* d_out, int out_size, void* d_ws, size_t ws_size,
                              hipStream_t stream) {
    const float* x  = (const float*)d_in[0];
    const int*   src = (const int*)d_in[1];
    const int*   dst = (const int*)d_in[2];
    const float* W1 = (const float*)d_in[3];
    const float* b1 = (const float*)d_in[4];
    const float* W2 = (const float*)d_in[5];
    const float* b2 = (const float*)d_in[6];
    const float* W3 = (const float*)d_in[7];
    const float* b3 = (const float*)d_in[8];
    const float* Wf = (const float*)d_in[9];
    const float* bf = (const float*)d_in[10];
    float* out = (float*)d_out;

    const int N = 50000;
    const int E = 800000;

    char* ws = (char*)d_ws;
    size_t off = 0;
    auto alloc = [&](size_t bytes) -> void* {
        void* p = (void*)(ws + off);
        off += (bytes + 511) & ~((size_t)511);
        return p;
    };
    int*   deg       = (int*)alloc((size_t)N * 4);
    float* dinv      = (float*)alloc((size_t)N * 4);
    int*   row_start = (int*)alloc((size_t)(N + 1) * 4);
    int*   fill      = (int*)alloc((size_t)N * 4);
    int*   partial   = (int*)alloc(64 * 4);
    int*   col       = (int*)alloc((size_t)E * 4);
    float* val       = (float*)alloc((size_t)E * 4);
    float* bufA      = (float*)alloc((size_t)N * 128 * 4);
    float* bufB      = (float*)alloc((size_t)N * 128 * 4);

    hipMemsetAsync(deg, 0, (size_t)N * 4, stream);
    hipMemsetAsync(fill, 0, (size_t)N * 4, stream);

    k_count_deg<<<(E + 255) / 256, 256, 0, stream>>>(dst, deg, E);
    k_dinv<<<(N + 255) / 256, 256, 0, stream>>>(deg, dinv, N);
    int NB = (N + 1023) / 1024;
    k_chunk_sums<<<NB, 1024, 0, stream>>>(deg, partial, N);
    k_scan_partials<<<1, 64, 0, stream>>>(partial, NB);
    k_chunk_scan<<<NB, 1024, 0, stream>>>(deg, partial, row_start, N);
    k_scatter<<<(E + 255) / 256, 256, 0, stream>>>(src, dst, row_start, fill, dinv, col, val, E);

    dim3 tb(16, 16);
    int gemmGrid = (N + 63) / 64;
    int aggGrid = (N * 64 + 255) / 256;

    // layer 1: t = x @ W1 ; h = relu(agg(t) + b1)
    k_gemm<128, 8><<<gemmGrid, tb, 0, stream>>>(x, W1, bufA, N);
    k_agg128<<<aggGrid, 256, 0, stream>>>(bufA, bufB, row_start, col, val, dinv, b1, N);
    // layer 2
    k_gemm<128, 8><<<gemmGrid, tb, 0, stream>>>(bufB, W2, bufA, N);
    k_agg128<<<aggGrid, 256, 0, stream>>>(bufA, bufB, row_start, col, val, dinv, b2, N);
    // layer 3 (transform to 64 dims first, then aggregate + fused final linear)
    k_gemm<64, 4><<<gemmGrid, tb, 0, stream>>>(bufB, W3, bufA, N);
    k_agg64_final<<<aggGrid, 256, 0, stream>>>(bufA, out, row_start, col, val, dinv, b3, Wf, bf, N);
}

// Round 5
// 376.602 us; speedup vs baseline: 1.8219x; 1.0693x over previous
//
#include <hip/hip_runtime.h>
#include <hip/hip_bf16.h>

typedef short bf16x8 __attribute__((ext_vector_type(8)));
typedef float f32x4 __attribute__((ext_vector_type(4)));

static __device__ __forceinline__ unsigned short f2bf_rne(float f) {
    unsigned int u = __float_as_uint(f);
    u += 0x7fff + ((u >> 16) & 1);
    return (unsigned short)(u >> 16);
}
static __device__ __forceinline__ float bf2f(unsigned short h) {
    return __uint_as_float(((unsigned int)h) << 16);
}

// ===================== preprocessing: degree / CSR build =====================

__global__ __launch_bounds__(256) void k_count_deg(const int* __restrict__ dst, int* __restrict__ deg, int E) {
    int e = blockIdx.x * blockDim.x + threadIdx.x;
    if (e < E) atomicAdd(&deg[dst[e]], 1);
}

__global__ __launch_bounds__(256) void k_dinv(const int* __restrict__ deg, float* __restrict__ dinv, int N) {
    int i = blockIdx.x * blockDim.x + threadIdx.x;
    if (i < N) dinv[i] = rsqrtf((float)deg[i] + 1.0f);
}

__global__ __launch_bounds__(1024) void k_chunk_sums(const int* __restrict__ deg, int* __restrict__ partial, int N) {
    __shared__ int wsum[16];
    int t = threadIdx.x;
    int i = blockIdx.x * 1024 + t;
    int v = (i < N) ? deg[i] : 0;
    for (int off = 32; off > 0; off >>= 1) v += __shfl_down(v, off, 64);
    if ((t & 63) == 0) wsum[t >> 6] = v;
    __syncthreads();
    if (t == 0) {
        int s = 0;
        #pragma unroll
        for (int k = 0; k < 16; ++k) s += wsum[k];
        partial[blockIdx.x] = s;
    }
}

__global__ void k_scan_partials(int* partial, int NB) {
    if (threadIdx.x == 0 && blockIdx.x == 0) {
        int run = 0;
        for (int b = 0; b < NB; ++b) { int t = partial[b]; partial[b] = run; run += t; }
    }
}

__global__ __launch_bounds__(1024) void k_chunk_scan(const int* __restrict__ deg, const int* __restrict__ partial,
                             int* __restrict__ row_start, int N) {
    __shared__ int s[1024];
    int t = threadIdx.x;
    int i = blockIdx.x * 1024 + t;
    int v = (i < N) ? deg[i] : 0;
    s[t] = v;
    __syncthreads();
    for (int off = 1; off < 1024; off <<= 1) {
        int x = (t >= off) ? s[t - off] : 0;
        __syncthreads();
        s[t] += x;
        __syncthreads();
    }
    if (i <= N) row_start[i] = partial[blockIdx.x] + s[t] - v;
}

// scatter (src, dinv[src]) packed into int2 so agg reads one coalesced 8B header/edge
__global__ __launch_bounds__(256) void k_scatter(const int* __restrict__ src, const int* __restrict__ dst,
                          const int* __restrict__ row_start, int* __restrict__ fill,
                          const float* __restrict__ dinv,
                          int2* __restrict__ cv, int E) {
    int e = blockIdx.x * blockDim.x + threadIdx.x;
    if (e < E) {
        int d = dst[e];
        int s = src[e];
        int r = atomicAdd(&fill[d], 1);
        cv[row_start[d] + r] = make_int2(s, __float_as_int(dinv[s]));
    }
}

// ===================== weight prep: split fp32 W[128 x BN] into hi/lo bf16, =====================
// fragment-ordered for mfma_f32_16x16x32_bf16 B-operand:
// B-frag for col-tile ct, k-chunk kc: lane = quad*16 + (n&15), holds k = kc*32+quad*8+j, j=0..7.
// slot(k,n) = (((kc*CT + ct)*4 + quad)*16 + (n&15))*8 + j   => wave loads 1 KB contiguous.

__global__ __launch_bounds__(256) void k_wprep(const float* __restrict__ W,
                                               unsigned short* __restrict__ hi,
                                               unsigned short* __restrict__ lo,
                                               int BN, int total) {
    int idx = blockIdx.x * blockDim.x + threadIdx.x;
    if (idx >= total) return;
    int k = idx / BN, n = idx % BN;
    float w = W[idx];
    unsigned short h = f2bf_rne(w);
    unsigned short l = f2bf_rne(w - bf2f(h));
    int CT = BN >> 4;
    int kc = k >> 5, quad = (k >> 3) & 3, j = k & 7;
    int ct = n >> 4, c = n & 15;
    int slot = (((kc * CT + ct) * 4 + quad) * 16 + c) * 8 + j;
    hi[slot] = h;
    lo[slot] = l;
}

// ===================== bf16-split MFMA GEMM: C[N x BN] = A[N x 128] @ W[128 x BN] ===============
// A = Ahi + Alo (bf16), W likewise (pre-split). acc += Ahi*Whi + Ahi*Wlo + Alo*Whi  (fp32 MFMA acc).
// Dropped Alo*Wlo term <= 2^-18 relative. Block = 256 thr (4 waves), BM=64 rows, full BN width.
// A staged in LDS in A-fragment order: lane m=lane&15 holds k=quad*8+j (m89-verified layout).

template<int BN>
__global__ __launch_bounds__(256, 2) void k_gemm_mfma(const float* __restrict__ A,
                        const unsigned short* __restrict__ Whi, const unsigned short* __restrict__ Wlo,
                        float* __restrict__ C, int N) {
    constexpr int CT = BN / 16;
    __shared__ unsigned short AhiS[4 * 64 * 8];   // [quad][row][j]
    __shared__ unsigned short AloS[4 * 64 * 8];
    const int tid = threadIdx.x;
    const int wave = tid >> 6;
    const int lane = tid & 63;
    const int quad = lane >> 4;
    const int c16 = lane & 15;
    const int row0 = blockIdx.x * 64;

    f32x4 acc[CT];
    #pragma unroll
    for (int t = 0; t < CT; ++t) acc[t] = (f32x4){0.f, 0.f, 0.f, 0.f};

    for (int kc = 0; kc < 4; ++kc) {
        // stage A: 64 rows x 32 k = 512 float4 loads -> split to bf16 hi/lo in frag order
        #pragma unroll
        for (int r = 0; r < 2; ++r) {
            int f4 = tid + r * 256;
            int arow = f4 >> 3;          // 0..63
            int c4 = f4 & 7;             // float4 index within 32-k chunk
            int grow = row0 + arow;
            float4 v = make_float4(0.f, 0.f, 0.f, 0.f);
            if (grow < N) v = *(const float4*)&A[(size_t)grow * 128 + kc * 32 + c4 * 4];
            unsigned short h0 = f2bf_rne(v.x), h1 = f2bf_rne(v.y), h2 = f2bf_rne(v.z), h3 = f2bf_rne(v.w);
            ushort4 hv = make_ushort4(h0, h1, h2, h3);
            ushort4 lv = make_ushort4(f2bf_rne(v.x - bf2f(h0)), f2bf_rne(v.y - bf2f(h1)),
                                      f2bf_rne(v.z - bf2f(h2)), f2bf_rne(v.w - bf2f(h3)));
            int q = c4 >> 1;
            int joff = (c4 & 1) * 4;
            int base = (q * 64 + arow) * 8 + joff;
            *(ushort4*)&AhiS[base] = hv;
            *(ushort4*)&AloS[base] = lv;
        }
        __syncthreads();

        int abase = (quad * 64 + wave * 16 + c16) * 8;
        bf16x8 ahi = *(const bf16x8*)&AhiS[abase];
        bf16x8 alo = *(const bf16x8*)&AloS[abase];

        #pragma unroll
        for (int ct = 0; ct < CT; ++ct) {
            size_t bslot = ((size_t)(kc * CT + ct) * 64 + lane) * 8;
            bf16x8 bhi = *(const bf16x8*)&Whi[bslot];
            bf16x8 blo = *(const bf16x8*)&Wlo[bslot];
            acc[ct] = __builtin_amdgcn_mfma_f32_16x16x32_bf16(ahi, bhi, acc[ct], 0, 0, 0);
            acc[ct] = __builtin_amdgcn_mfma_f32_16x16x32_bf16(ahi, blo, acc[ct], 0, 0, 0);
            acc[ct] = __builtin_amdgcn_mfma_f32_16x16x32_bf16(alo, bhi, acc[ct], 0, 0, 0);
        }
        __syncthreads();
    }

    // C/D layout: col = lane&15, row = quad*4 + reg (dtype-independent, m89/m101)
    #pragma unroll
    for (int ct = 0; ct < CT; ++ct) {
        #pragma unroll
        for (int r = 0; r < 4; ++r) {
            int grow = row0 + wave * 16 + quad * 4 + r;
            if (grow < N) C[(size_t)grow * BN + ct * 16 + c16] = acc[ct][r];
        }
    }
}

// ===================== aggregation =====================
// One wave per node; (col,val) header for 64 edges in one coalesced int2 load, broadcast
// via __shfl; 16 gathers in flight (R4: 8-deep was latency-bound at 58.5 us).

__global__ __launch_bounds__(256) void k_agg128(const float* __restrict__ t, float* __restrict__ outp,
                      const int* __restrict__ row_start, const int2* __restrict__ cv,
                      const float* __restrict__ dinv, const float* __restrict__ bias,
                      int N) {
    int gid = blockIdx.x * blockDim.x + threadIdx.x;
    int node = gid >> 6;
    int lane = gid & 63;
    if (node >= N) return;
    int p = row_start[node];
    int end = row_start[node + 1];
    const float2* tp = (const float2*)t;
    float2 acc[4];
    #pragma unroll
    for (int j = 0; j < 4; ++j) acc[j] = make_float2(0.f, 0.f);

    while (p < end) {
        int idx = p + lane;
        int2 h = (idx < end) ? cv[idx] : make_int2(0, 0);
        int myc = h.x;
        float myw = __int_as_float(h.y);
        int cnt = min(end - p, 64);
        int e = 0;
        for (; e + 16 <= cnt; e += 16) {
            int s[16]; float w[16];
            #pragma unroll
            for (int j = 0; j < 16; ++j) { s[j] = __shfl(myc, e + j); w[j] = __shfl(myw, e + j); }
            float2 v[16];
            #pragma unroll
            for (int j = 0; j < 16; ++j) v[j] = tp[s[j] * 64 + lane];
            #pragma unroll
            for (int j = 0; j < 16; ++j) {
                acc[j & 3].x += w[j] * v[j].x;
                acc[j & 3].y += w[j] * v[j].y;
            }
        }
        for (; e + 4 <= cnt; e += 4) {
            int s[4]; float w[4];
            #pragma unroll
            for (int j = 0; j < 4; ++j) { s[j] = __shfl(myc, e + j); w[j] = __shfl(myw, e + j); }
            float2 v[4];
            #pragma unroll
            for (int j = 0; j < 4; ++j) v[j] = tp[s[j] * 64 + lane];
            #pragma unroll
            for (int j = 0; j < 4; ++j) {
                acc[j].x += w[j] * v[j].x;
                acc[j].y += w[j] * v[j].y;
            }
        }
        for (; e < cnt; ++e) {
            int s0 = __shfl(myc, e); float w0 = __shfl(myw, e);
            float2 v0 = tp[s0 * 64 + lane];
            acc[0].x += w0 * v0.x;
            acc[0].y += w0 * v0.y;
        }
        p += 64;
    }
    float di = dinv[node];
    float2 sv = tp[node * 64 + lane];
    float2 bv = ((const float2*)bias)[lane];
    float sx = acc[0].x + acc[1].x + acc[2].x + acc[3].x;
    float sy = acc[0].y + acc[1].y + acc[2].y + acc[3].y;
    float2 r;
    r.x = fmaxf(di * sx + di * di * sv.x + bv.x, 0.f);
    r.y = fmaxf(di * sy + di * di * sv.y + bv.y, 0.f);
    ((float2*)outp)[node * 64 + lane] = r;
}

// layer-3 aggregation (D=64) fused with final linear: out[i] = relu(agg_i + b) . Wf + bf
__global__ __launch_bounds__(256) void k_agg64_final(const float* __restrict__ t, float* __restrict__ outp,
                      const int* __restrict__ row_start, const int2* __restrict__ cv,
                      const float* __restrict__ dinv, const float* __restrict__ bias,
                      const float* __restrict__ Wf, const float* __restrict__ bf,
                      int N) {
    int gid = blockIdx.x * blockDim.x + threadIdx.x;
    int node = gid >> 6;
    int lane = gid & 63;
    if (node >= N) return;
    int p = row_start[node];
    int end = row_start[node + 1];
    float acc[4] = {0.f, 0.f, 0.f, 0.f};

    while (p < end) {
        int idx = p + lane;
        int2 h = (idx < end) ? cv[idx] : make_int2(0, 0);
        int myc = h.x;
        float myw = __int_as_float(h.y);
        int cnt = min(end - p, 64);
        int e = 0;
        for (; e + 16 <= cnt; e += 16) {
            int s[16]; float w[16];
            #pragma unroll
            for (int j = 0; j < 16; ++j) { s[j] = __shfl(myc, e + j); w[j] = __shfl(myw, e + j); }
            float v[16];
            #pragma unroll
            for (int j = 0; j < 16; ++j) v[j] = t[s[j] * 64 + lane];
            #pragma unroll
            for (int j = 0; j < 16; ++j) acc[j & 3] += w[j] * v[j];
        }
        for (; e + 4 <= cnt; e += 4) {
            int s[4]; float w[4];
            #pragma unroll
            for (int j = 0; j < 4; ++j) { s[j] = __shfl(myc, e + j); w[j] = __shfl(myw, e + j); }
            float v[4];
            #pragma unroll
            for (int j = 0; j < 4; ++j) v[j] = t[s[j] * 64 + lane];
            #pragma unroll
            for (int j = 0; j < 4; ++j) acc[j] += w[j] * v[j];
        }
        for (; e < cnt; ++e) {
            int s0 = __shfl(myc, e); float w0 = __shfl(myw, e);
            acc[0] += w0 * t[s0 * 64 + lane];
        }
        p += 64;
    }
    float di = dinv[node];
    float r = di * (acc[0] + acc[1] + acc[2] + acc[3]) + di * di * t[node * 64 + lane] + bias[lane];
    r = fmaxf(r, 0.f);
    float v = r * Wf[lane];
    for (int off = 32; off > 0; off >>= 1) v += __shfl_down(v, off, 64);
    if (lane == 0) outp[node] = v + bf[0];
}

// ===================== launch =====================

extern "C" void kernel_launch(void* const* d_in, const int* in_sizes, int n_in,
                              void* d_out, int out_size, void* d_ws, size_t ws_size,
                              hipStream_t stream) {
    const float* x  = (const float*)d_in[0];
    const int*   src = (const int*)d_in[1];
    const int*   dst = (const int*)d_in[2];
    const float* W1 = (const float*)d_in[3];
    const float* b1 = (const float*)d_in[4];
    const float* W2 = (const float*)d_in[5];
    const float* b2 = (const float*)d_in[6];
    const float* W3 = (const float*)d_in[7];
    const float* b3 = (const float*)d_in[8];
    const float* Wf = (const float*)d_in[9];
    const float* bf = (const float*)d_in[10];
    float* out = (float*)d_out;

    const int N = 50000;
    const int E = 800000;

    char* ws = (char*)d_ws;
    size_t off = 0;
    auto alloc = [&](size_t bytes) -> void* {
        void* p = (void*)(ws + off);
        off += (bytes + 511) & ~((size_t)511);
        return p;
    };
    int*   deg       = (int*)alloc((size_t)N * 4);
    float* dinv      = (float*)alloc((size_t)N * 4);
    int*   row_start = (int*)alloc((size_t)(N + 1) * 4);
    int*   fill      = (int*)alloc((size_t)N * 4);
    int*   partial   = (int*)alloc(64 * 4);
    int2*  cv        = (int2*)alloc((size_t)E * 8);
    float* bufA      = (float*)alloc((size_t)N * 128 * 4);
    float* bufB      = (float*)alloc((size_t)N * 128 * 4);
    unsigned short* W1hi = (unsigned short*)alloc(128 * 128 * 2);
    unsigned short* W1lo = (unsigned short*)alloc(128 * 128 * 2);
    unsigned short* W2hi = (unsigned short*)alloc(128 * 128 * 2);
    unsigned short* W2lo = (unsigned short*)alloc(128 * 128 * 2);
    unsigned short* W3hi = (unsigned short*)alloc(128 * 64 * 2);
    unsigned short* W3lo = (unsigned short*)alloc(128 * 64 * 2);

    hipMemsetAsync(deg, 0, (size_t)N * 4, stream);
    hipMemsetAsync(fill, 0, (size_t)N * 4, stream);

    k_count_deg<<<(E + 255) / 256, 256, 0, stream>>>(dst, deg, E);
    k_dinv<<<(N + 255) / 256, 256, 0, stream>>>(deg, dinv, N);
    int NB = (N + 1023) / 1024;
    k_chunk_sums<<<NB, 1024, 0, stream>>>(deg, partial, N);
    k_scan_partials<<<1, 64, 0, stream>>>(partial, NB);
    k_chunk_scan<<<NB, 1024, 0, stream>>>(deg, partial, row_start, N);
    k_scatter<<<(E + 255) / 256, 256, 0, stream>>>(src, dst, row_start, fill, dinv, cv, E);

    k_wprep<<<(128 * 128 + 255) / 256, 256, 0, stream>>>(W1, W1hi, W1lo, 128, 128 * 128);
    k_wprep<<<(128 * 128 + 255) / 256, 256, 0, stream>>>(W2, W2hi, W2lo, 128, 128 * 128);
    k_wprep<<<(128 * 64 + 255) / 256, 256, 0, stream>>>(W3, W3hi, W3lo, 64, 128 * 64);

    int gemmGrid = (N + 63) / 64;
    int aggGrid = (N * 64 + 255) / 256;

    // layer 1: t = x @ W1 ; h = relu(agg(t) + b1)
    k_gemm_mfma<128><<<gemmGrid, 256, 0, stream>>>(x, W1hi, W1lo, bufA, N);
    k_agg128<<<aggGrid, 256, 0, stream>>>(bufA, bufB, row_start, cv, dinv, b1, N);
    // layer 2
    k_gemm_mfma<128><<<gemmGrid, 256, 0, stream>>>(bufB, W2hi, W2lo, bufA, N);
    k_agg128<<<aggGrid, 256, 0, stream>>>(bufA, bufB, row_start, cv, dinv, b2, N);
    // layer 3 (transform to 64 dims first, then aggregate + fused final linear)
    k_gemm_mfma<64><<<gemmGrid, 256, 0, stream>>>(bufB, W3hi, W3lo, bufA, N);
    k_agg64_final<<<aggGrid, 256, 0, stream>>>(bufA, out, row_start, cv, dinv, b3, Wf, bf, N);
}